// Round 1
// baseline (204.086 us; speedup 1.0000x reference)
//
#include <hip/hip_runtime.h>

// Problem constants (fixed by setup_inputs: B=16, T=16, W=256)
#define WDIM 256
#define FRAME (WDIM * WDIM)        // 65536 elems per frame
#define NFRAMES 256                // B*T
#define NTOT ((long long)NFRAMES * FRAME)  // 16777216
#define BLOCK 1024                 // 16 waves

// Merge helper for the (max, cnt, sum_r, sum_c) monoid:
// strictly greater max wins; equal max merges the centroid sums.
__device__ inline void monoid_merge(float& m, float& cnt, float& sr, float& sc,
                                    float m2, float cnt2, float sr2, float sc2) {
    if (m2 > m) { m = m2; cnt = cnt2; sr = sr2; sc = sc2; }
    else if (m2 == m) { cnt += cnt2; sr += sr2; sc += sc2; }
}

__global__ __launch_bounds__(BLOCK)
void floss_main(const float* __restrict__ input, const float* __restrict__ target,
                double* __restrict__ acc) {
    const int frame = blockIdx.x;
    const float* __restrict__ t = target + (size_t)frame * FRAME;
    const float* __restrict__ p = input  + (size_t)frame * FRAME;
    const int tid  = threadIdx.x;
    const int lane = tid & 63;
    const int wave = tid >> 6;

    // ---- Pass 1: single-pass argmax-centroid via monoid reduction ----
    float m = -1.0f, cnt = 0.0f, sr = 0.0f, sc = 0.0f;
    for (int i = tid; i < FRAME / 4; i += BLOCK) {
        float4 v = ((const float4*)t)[i];
        const int f0 = i * 4;
        float vv[4] = {v.x, v.y, v.z, v.w};
        #pragma unroll
        for (int k = 0; k < 4; ++k) {
            const int f = f0 + k;
            const float r = (float)(f >> 8);
            const float c = (float)(f & 255);
            if (vv[k] > m)       { m = vv[k]; cnt = 1.0f; sr = r; sc = c; }
            else if (vv[k] == m) { cnt += 1.0f; sr += r; sc += c; }
        }
    }
    // wave (64-lane) reduction
    #pragma unroll
    for (int off = 32; off > 0; off >>= 1) {
        float m2   = __shfl_down(m, off);
        float c2   = __shfl_down(cnt, off);
        float sr2  = __shfl_down(sr, off);
        float sc2  = __shfl_down(sc, off);
        monoid_merge(m, cnt, sr, sc, m2, c2, sr2, sc2);
    }
    __shared__ float sm[16], scnt[16], ssr[16], ssc[16];
    __shared__ float sx, sy;
    if (lane == 0) { sm[wave] = m; scnt[wave] = cnt; ssr[wave] = sr; ssc[wave] = sc; }
    __syncthreads();
    if (tid == 0) {
        m = sm[0]; cnt = scnt[0]; sr = ssr[0]; sc = ssc[0];
        #pragma unroll
        for (int w2 = 1; w2 < 16; ++w2)
            monoid_merge(m, cnt, sr, sc, sm[w2], scnt[w2], ssr[w2], ssc[w2]);
        sx = sr / cnt;   // mean row of argmax pixels
        sy = sc / cnt;   // mean col
    }
    __syncthreads();
    const float x = sx, y = sy;

    // ---- Pass 2: weighted BCE accumulation ----
    float local = 0.0f;
    for (int i = tid; i < FRAME / 4; i += BLOCK) {
        float4 tv = ((const float4*)t)[i];
        float4 pv = ((const float4*)p)[i];
        const int f0 = i * 4;
        float tvv[4] = {tv.x, tv.y, tv.z, tv.w};
        float pvv[4] = {pv.x, pv.y, pv.z, pv.w};
        #pragma unroll
        for (int k = 0; k < 4; ++k) {
            const int f = f0 + k;
            const float dr = (float)(f >> 8) - x;
            const float dc = (float)(f & 255) - y;
            const float dist = sqrtf(dr * dr + dc * dc);
            const float w = 256.0f / (dist + 1.0f);
            const float tt = tvv[k], pp = pvv[k];
            const float lp  = fmaxf(__logf(pp), -100.0f);
            const float l1p = fmaxf(log1pf(-pp), -100.0f);
            local += w * (tt * lp + (1.0f - tt) * l1p);
        }
    }
    #pragma unroll
    for (int off = 32; off > 0; off >>= 1) local += __shfl_down(local, off);
    __shared__ float sacc[16];
    if (lane == 0) sacc[wave] = local;
    __syncthreads();
    if (tid == 0) {
        float s = 0.0f;
        #pragma unroll
        for (int w2 = 0; w2 < 16; ++w2) s += sacc[w2];
        atomicAdd(acc, (double)s);
    }
}

__global__ void floss_final(const double* __restrict__ acc, float* __restrict__ out) {
    if (threadIdx.x == 0 && blockIdx.x == 0)
        out[0] = (float)(-acc[0] / (double)NTOT);
}

extern "C" void kernel_launch(void* const* d_in, const int* in_sizes, int n_in,
                              void* d_out, int out_size, void* d_ws, size_t ws_size,
                              hipStream_t stream) {
    const float* input  = (const float*)d_in[0];  // [B,1,T,W,W] == flat [B,T,W,W]
    const float* target = (const float*)d_in[1];  // [B,T,W,W]
    float* out = (float*)d_out;
    double* acc = (double*)d_ws;

    // d_ws is re-poisoned to 0xAA before every launch — zero the accumulator.
    hipMemsetAsync(acc, 0, sizeof(double), stream);
    floss_main<<<NFRAMES, BLOCK, 0, stream>>>(input, target, acc);
    floss_final<<<1, 64, 0, stream>>>(acc, out);
}

// Round 2
// 166.105 us; speedup vs baseline: 1.2287x; 1.2287x over previous
//
#include <hip/hip_runtime.h>

// Problem constants (fixed by setup_inputs: B=16, T=16, W=256)
#define WDIM 256
#define FRAME (WDIM * WDIM)        // 65536 elems per frame
#define NFRAMES 256                // B*T
#define NTOT ((long long)NFRAMES * FRAME)  // 16777216

// ws layout: float4 partials[1024] (16 KB) | double acc (offset 16384)
#define ACC_OFFSET 16384

// Merge helper for the (max, cnt, sum_r, sum_c) monoid.
__device__ inline void monoid_merge(float& m, float& cnt, float& sr, float& sc,
                                    float m2, float cnt2, float sr2, float sc2) {
    if (m2 > m) { m = m2; cnt = cnt2; sr = sr2; sc = sc2; }
    else if (m2 == m) { cnt += cnt2; sr += sr2; sc += sc2; }
}

// ---- Kernel A: per-quarter-frame argmax-centroid partials ----
// grid = NFRAMES*4 = 1024 blocks x 256 threads; block handles 16384 elems.
__global__ __launch_bounds__(256)
void floss_partial(const float* __restrict__ target, float4* __restrict__ partials) {
    const int blk = blockIdx.x;
    const int frame = blk >> 2;
    const int quarter = blk & 3;
    const float* __restrict__ t = target + (size_t)frame * FRAME;
    const int tid = threadIdx.x;
    const int lane = tid & 63, wave = tid >> 6;
    const int base4 = quarter * 4096;   // float4 index base within frame

    float m = -1.0f, cnt = 0.0f, sr = 0.0f, sc = 0.0f;
    #pragma unroll 4
    for (int k = 0; k < 16; ++k) {
        const int i4 = base4 + k * 256 + tid;
        const float4 v = ((const float4*)t)[i4];
        const int f = i4 * 4;                 // elem index within frame
        const float row = (float)(f >> 8);    // float4 never crosses a row
        const float colb = (float)(f & 255);
        const float vv[4] = {v.x, v.y, v.z, v.w};
        #pragma unroll
        for (int j = 0; j < 4; ++j) {
            const float val = vv[j];
            if (val > m)       { m = val; cnt = 1.0f; sr = row; sc = colb + (float)j; }
            else if (val == m) { cnt += 1.0f; sr += row; sc += colb + (float)j; }
        }
    }
    #pragma unroll
    for (int off = 32; off > 0; off >>= 1) {
        float m2  = __shfl_down(m, off);
        float c2  = __shfl_down(cnt, off);
        float sr2 = __shfl_down(sr, off);
        float sc2 = __shfl_down(sc, off);
        monoid_merge(m, cnt, sr, sc, m2, c2, sr2, sc2);
    }
    __shared__ float sm[4], scnt[4], ssr[4], ssc[4];
    if (lane == 0) { sm[wave] = m; scnt[wave] = cnt; ssr[wave] = sr; ssc[wave] = sc; }
    __syncthreads();
    if (tid == 0) {
        m = sm[0]; cnt = scnt[0]; sr = ssr[0]; sc = ssc[0];
        #pragma unroll
        for (int w2 = 1; w2 < 4; ++w2)
            monoid_merge(m, cnt, sr, sc, sm[w2], scnt[w2], ssr[w2], ssc[w2]);
        partials[blk] = make_float4(m, cnt, sr, sc);
    }
}

// ---- Kernel B: weighted BCE over 1/8 frame per block ----
// grid = NFRAMES*8 = 2048 blocks x 256 threads; block handles 8192 elems.
__global__ __launch_bounds__(256)
void floss_bce(const float* __restrict__ input, const float* __restrict__ target,
               const float4* __restrict__ partials, double* __restrict__ acc) {
    const int blk = blockIdx.x;
    const int frame = blk >> 3;
    const int seg = blk & 7;
    const int tid = threadIdx.x;
    const int lane = tid & 63, wave = tid >> 6;

    // Every thread redundantly merges its frame's 4 partials (L2-hot, 64 B).
    float m, cnt, sr, sc;
    {
        const float4 p0 = partials[frame * 4 + 0];
        m = p0.x; cnt = p0.y; sr = p0.z; sc = p0.w;
        #pragma unroll
        for (int q = 1; q < 4; ++q) {
            const float4 pq = partials[frame * 4 + q];
            monoid_merge(m, cnt, sr, sc, pq.x, pq.y, pq.z, pq.w);
        }
    }
    const float rc = __builtin_amdgcn_rcpf(cnt);  // cnt is a small exact int
    const float x = sr * rc;   // mean row (sums are exact ints < 2^24)
    const float y = sc * rc;   // mean col

    const float* __restrict__ t = target + (size_t)frame * FRAME;
    const float* __restrict__ p = input  + (size_t)frame * FRAME;
    const int base4 = seg * 2048;  // float4 base within frame

    float local = 0.0f;
    #pragma unroll 2
    for (int k = 0; k < 8; ++k) {
        const int i4 = base4 + k * 256 + tid;
        const float4 tv = ((const float4*)t)[i4];
        const float4 pv = ((const float4*)p)[i4];
        const int f = i4 * 4;
        const float dr = (float)(f >> 8) - x;
        const float dr2 = dr * dr;
        const float dcb = (float)(f & 255) - y;
        const float tvv[4] = {tv.x, tv.y, tv.z, tv.w};
        const float pvv[4] = {pv.x, pv.y, pv.z, pv.w};
        #pragma unroll
        for (int j = 0; j < 4; ++j) {
            const float dc = dcb + (float)j;
            const float dist = __builtin_amdgcn_sqrtf(fmaf(dc, dc, dr2));
            const float w = 256.0f * __builtin_amdgcn_rcpf(dist + 1.0f);
            const float tt = tvv[j], pp = pvv[j];
            const float lp  = fmaxf(__logf(pp), -100.0f);          // v_log_f32
            const float l1p = fmaxf(__logf(1.0f - pp), -100.0f);   // exact 1-p for p>=0.5
            // t*lp + (1-t)*l1p == l1p + t*(lp - l1p)
            local += w * fmaf(tt, lp - l1p, l1p);
        }
    }
    #pragma unroll
    for (int off = 32; off > 0; off >>= 1) local += __shfl_down(local, off);
    __shared__ float sacc[4];
    if (lane == 0) sacc[wave] = local;
    __syncthreads();
    if (tid == 0) {
        atomicAdd(acc, (double)(sacc[0] + sacc[1] + sacc[2] + sacc[3]));
    }
}

__global__ void floss_final(const double* __restrict__ acc, float* __restrict__ out) {
    if (threadIdx.x == 0 && blockIdx.x == 0)
        out[0] = (float)(-acc[0] / (double)NTOT);
}

extern "C" void kernel_launch(void* const* d_in, const int* in_sizes, int n_in,
                              void* d_out, int out_size, void* d_ws, size_t ws_size,
                              hipStream_t stream) {
    const float* input  = (const float*)d_in[0];  // [B,1,T,W,W] == flat [B,T,W,W]
    const float* target = (const float*)d_in[1];  // [B,T,W,W]
    float* out = (float*)d_out;
    float4* partials = (float4*)d_ws;
    double* acc = (double*)((char*)d_ws + ACC_OFFSET);

    // d_ws is re-poisoned to 0xAA before every launch — zero the accumulator.
    // (partials are fully overwritten by floss_partial, no memset needed)
    hipMemsetAsync(acc, 0, sizeof(double), stream);
    floss_partial<<<NFRAMES * 4, 256, 0, stream>>>(target, partials);
    floss_bce<<<NFRAMES * 8, 256, 0, stream>>>(input, target, partials, acc);
    floss_final<<<1, 64, 0, stream>>>(acc, out);
}

// Round 3
// 159.372 us; speedup vs baseline: 1.2806x; 1.0422x over previous
//
#include <hip/hip_runtime.h>

// Problem constants (fixed by setup_inputs: B=16, T=16, W=256)
#define WDIM 256
#define FRAME (WDIM * WDIM)        // 65536 elems per frame
#define NFRAMES 256                // B*T
#define NTOT ((long long)NFRAMES * FRAME)  // 16777216

// ws layout: float4 partials[1024] (16 KB) | double acc (offset 16384)
#define ACC_OFFSET 16384

// Merge helper for the (max, cnt, sum_r, sum_c) monoid.
__device__ inline void monoid_merge(float& m, float& cnt, float& sr, float& sc,
                                    float m2, float cnt2, float sr2, float sc2) {
    if (m2 > m) { m = m2; cnt = cnt2; sr = sr2; sc = sc2; }
    else if (m2 == m) { cnt += cnt2; sr += sr2; sc += sc2; }
}

// ---- Kernel A: per-quarter-frame argmax-centroid partials ----
// grid = NFRAMES*4 = 1024 blocks x 256 threads; block handles 16384 elems.
// All 16 float4 loads issued up front for latency hiding (ILP over occupancy).
__global__ __launch_bounds__(256)
void floss_partial(const float* __restrict__ target, float4* __restrict__ partials,
                   double* __restrict__ acc) {
    const int blk = blockIdx.x;
    const int frame = blk >> 2;
    const int quarter = blk & 3;
    const int tid = threadIdx.x;
    const int lane = tid & 63, wave = tid >> 6;

    // zero the global accumulator for kernel B (ws is poisoned each call)
    if (blk == 0 && tid == 0) *acc = 0.0;

    const float4* __restrict__ t4 =
        (const float4*)(target + (size_t)frame * FRAME) + quarter * 4096 + tid;

    float4 v[16];
    #pragma unroll
    for (int k = 0; k < 16; ++k) v[k] = t4[k * 256];

    // elem index: row = quarter*64 + 4k + wave ; col = 4*lane + j
    const float rowb = (float)(quarter * 64 + wave);
    const float colb = (float)(lane * 4);

    float m = -1.0f, cnt = 0.0f, sr = 0.0f, sc = 0.0f;
    #pragma unroll
    for (int k = 0; k < 16; ++k) {
        const float row = rowb + (float)(4 * k);
        const float vv[4] = {v[k].x, v[k].y, v[k].z, v[k].w};
        #pragma unroll
        for (int j = 0; j < 4; ++j) {
            const float val = vv[j];
            const float col = colb + (float)j;
            if (val > m)       { m = val; cnt = 1.0f; sr = row; sc = col; }
            else if (val == m) { cnt += 1.0f; sr += row; sc += col; }
        }
    }
    #pragma unroll
    for (int off = 32; off > 0; off >>= 1) {
        float m2  = __shfl_down(m, off);
        float c2  = __shfl_down(cnt, off);
        float sr2 = __shfl_down(sr, off);
        float sc2 = __shfl_down(sc, off);
        monoid_merge(m, cnt, sr, sc, m2, c2, sr2, sc2);
    }
    __shared__ float sm[4], scnt[4], ssr[4], ssc[4];
    if (lane == 0) { sm[wave] = m; scnt[wave] = cnt; ssr[wave] = sr; ssc[wave] = sc; }
    __syncthreads();
    if (tid == 0) {
        m = sm[0]; cnt = scnt[0]; sr = ssr[0]; sc = ssc[0];
        #pragma unroll
        for (int w2 = 1; w2 < 4; ++w2)
            monoid_merge(m, cnt, sr, sc, sm[w2], scnt[w2], ssr[w2], ssc[w2]);
        partials[blk] = make_float4(m, cnt, sr, sc);
    }
}

// ---- Kernel B: weighted BCE over 1/8 frame per block ----
// grid = NFRAMES*8 = 2048 blocks x 256 threads; block handles 8192 elems.
// All 16 float4 loads (8 target + 8 input) issued up front.
__global__ __launch_bounds__(256)
void floss_bce(const float* __restrict__ input, const float* __restrict__ target,
               const float4* __restrict__ partials, double* __restrict__ acc) {
    const int blk = blockIdx.x;
    const int frame = blk >> 3;
    const int seg = blk & 7;
    const int tid = threadIdx.x;
    const int lane = tid & 63, wave = tid >> 6;

    const float4* __restrict__ t4 =
        (const float4*)(target + (size_t)frame * FRAME) + seg * 2048 + tid;
    const float4* __restrict__ p4 =
        (const float4*)(input + (size_t)frame * FRAME) + seg * 2048 + tid;

    float4 tv[8], pv[8];
    #pragma unroll
    for (int k = 0; k < 8; ++k) { tv[k] = t4[k * 256]; pv[k] = p4[k * 256]; }

    // Merge this frame's 4 partials (64 B, L2-hot).
    float m, cnt, sr, sc;
    {
        const float4 p0 = partials[frame * 4 + 0];
        m = p0.x; cnt = p0.y; sr = p0.z; sc = p0.w;
        #pragma unroll
        for (int q = 1; q < 4; ++q) {
            const float4 pq = partials[frame * 4 + q];
            monoid_merge(m, cnt, sr, sc, pq.x, pq.y, pq.z, pq.w);
        }
    }
    const float rc = __builtin_amdgcn_rcpf(cnt);  // cnt is a small exact int
    const float x = sr * rc;   // mean row
    const float y = sc * rc;   // mean col

    // elem index: row = seg*32 + 4k + wave ; col = 4*lane + j
    const float drb = (float)(seg * 32 + wave) - x;
    const float dcb = (float)(lane * 4) - y;
    float dc2[4];
    #pragma unroll
    for (int j = 0; j < 4; ++j) { const float d = dcb + (float)j; dc2[j] = d * d; }

    float acc0 = 0.0f, acc1 = 0.0f;
    #pragma unroll
    for (int k = 0; k < 8; ++k) {
        const float dr = drb + (float)(4 * k);
        const float dr2 = dr * dr;
        const float tvv[4] = {tv[k].x, tv[k].y, tv[k].z, tv[k].w};
        const float pvv[4] = {pv[k].x, pv[k].y, pv[k].z, pv[k].w};
        #pragma unroll
        for (int j = 0; j < 4; ++j) {
            const float dist = __builtin_amdgcn_sqrtf(dr2 + dc2[j]);
            const float w = 256.0f * __builtin_amdgcn_rcpf(dist + 1.0f);
            const float tt = tvv[j], pp = pvv[j];
            const float lp  = fmaxf(__logf(pp), -100.0f);          // v_log_f32
            const float l1p = fmaxf(__logf(1.0f - pp), -100.0f);   // exact 1-p for p>=0.5
            // t*lp + (1-t)*l1p == l1p + t*(lp - l1p)
            if (j & 1) acc1 += w * fmaf(tt, lp - l1p, l1p);
            else       acc0 += w * fmaf(tt, lp - l1p, l1p);
        }
    }
    float local = acc0 + acc1;
    #pragma unroll
    for (int off = 32; off > 0; off >>= 1) local += __shfl_down(local, off);
    __shared__ float sacc[4];
    if (lane == 0) sacc[wave] = local;
    __syncthreads();
    if (tid == 0) {
        atomicAdd(acc, (double)(sacc[0] + sacc[1] + sacc[2] + sacc[3]));
    }
}

__global__ void floss_final(const double* __restrict__ acc, float* __restrict__ out) {
    if (threadIdx.x == 0 && blockIdx.x == 0)
        out[0] = (float)(-acc[0] / (double)NTOT);
}

extern "C" void kernel_launch(void* const* d_in, const int* in_sizes, int n_in,
                              void* d_out, int out_size, void* d_ws, size_t ws_size,
                              hipStream_t stream) {
    const float* input  = (const float*)d_in[0];  // [B,1,T,W,W] == flat [B,T,W,W]
    const float* target = (const float*)d_in[1];  // [B,T,W,W]
    float* out = (float*)d_out;
    float4* partials = (float4*)d_ws;
    double* acc = (double*)((char*)d_ws + ACC_OFFSET);

    floss_partial<<<NFRAMES * 4, 256, 0, stream>>>(target, partials, acc);
    floss_bce<<<NFRAMES * 8, 256, 0, stream>>>(input, target, partials, acc);
    floss_final<<<1, 64, 0, stream>>>(acc, out);
}

// Round 4
// 148.568 us; speedup vs baseline: 1.3737x; 1.0727x over previous
//
#include <hip/hip_runtime.h>
#include <hip/hip_bf16.h>
#include <string.h>

// Problem constants (fixed by setup_inputs: B=16, T=16, W=256)
#define WDIM 256
#define FRAME (WDIM * WDIM)        // 65536 elems per frame
#define NFRAMES 256                // B*T
#define NTOT ((long long)NFRAMES * FRAME)  // 16777216
#define BLOCK 1024                 // 16 waves; 1 block per frame

// ws layout: double blocksum[256] (2 KB), fully overwritten every call.

// Merge helper for the (max, cnt, sum_r, sum_c) monoid.
__device__ inline void monoid_merge(float& m, float& cnt, float& sr, float& sc,
                                    float m2, float cnt2, float sr2, float sc2) {
    if (m2 > m) { m = m2; cnt = cnt2; sr = sr2; sc = sc2; }
    else if (m2 == m) { cnt += cnt2; sr += sr2; sc += sc2; }
}

__device__ inline unsigned int pack_bf16x2(float a, float b) {
    __hip_bfloat162 h = __float22bfloat162_rn(make_float2(a, b));
    unsigned int u; memcpy(&u, &h, 4); return u;
}

// Fused kernel: one block per frame. Pass 1: stream target from HBM once,
// monoid on exact fp32 + stage bf16 copy in LDS. Block-reduce centroid.
// Pass 2: input from HBM (single stream), target from LDS. Per-block double
// partial sum to ws.
__global__ __launch_bounds__(BLOCK, 4)
void floss_fused(const float* __restrict__ input, const float* __restrict__ target,
                 double* __restrict__ blocksum) {
    __shared__ unsigned int lds_t[FRAME / 2];   // 128 KiB: frame as bf16 pairs
    __shared__ float sm[16], scnt[16], ssr[16], ssc[16];
    __shared__ float sx, sy;

    const int frame = blockIdx.x;
    const int tid = threadIdx.x;
    const int lane = tid & 63, wave = tid >> 6;

    const float4* __restrict__ t4 = (const float4*)(target + (size_t)frame * FRAME);
    const float4* __restrict__ p4 = (const float4*)(input  + (size_t)frame * FRAME);

    // ---- Pass 1: monoid + LDS staging ----
    // elem f = 4*(k*1024+tid): row = 16k + wave, col = 4*lane + j
    const float colb = (float)(lane * 4);
    float m = -1.0f, cnt = 0.0f, sr = 0.0f, sc = 0.0f;
    #pragma unroll
    for (int k = 0; k < 16; ++k) {
        const int i4 = k * 1024 + tid;
        const float4 v = t4[i4];
        const float row = (float)(16 * k + wave);
        const float vv[4] = {v.x, v.y, v.z, v.w};
        #pragma unroll
        for (int j = 0; j < 4; ++j) {
            const float val = vv[j];
            if (val > m)       { m = val; cnt = 1.0f; sr = row; sc = colb + (float)j; }
            else if (val == m) { cnt += 1.0f; sr += row; sc += colb + (float)j; }
        }
        *(uint2*)&lds_t[2 * i4] =
            make_uint2(pack_bf16x2(v.x, v.y), pack_bf16x2(v.z, v.w));
    }
    #pragma unroll
    for (int off = 32; off > 0; off >>= 1) {
        float m2  = __shfl_down(m, off);
        float c2  = __shfl_down(cnt, off);
        float sr2 = __shfl_down(sr, off);
        float sc2 = __shfl_down(sc, off);
        monoid_merge(m, cnt, sr, sc, m2, c2, sr2, sc2);
    }
    if (lane == 0) { sm[wave] = m; scnt[wave] = cnt; ssr[wave] = sr; ssc[wave] = sc; }
    __syncthreads();   // covers sm[] AND lds_t[] staging writes
    if (tid == 0) {
        m = sm[0]; cnt = scnt[0]; sr = ssr[0]; sc = ssc[0];
        #pragma unroll
        for (int w2 = 1; w2 < 16; ++w2)
            monoid_merge(m, cnt, sr, sc, sm[w2], scnt[w2], ssr[w2], ssc[w2]);
        const float rc = __builtin_amdgcn_rcpf(cnt);  // cnt: small exact int
        sx = sr * rc;   // mean row
        sy = sc * rc;   // mean col
    }
    __syncthreads();
    const float x = sx, y = sy;

    // ---- Pass 2: BCE with input from HBM, target from LDS ----
    const float drb = (float)wave - x;
    float dc2[4];
    #pragma unroll
    for (int j = 0; j < 4; ++j) {
        const float d = colb + (float)j - y;
        dc2[j] = d * d;
    }

    float acc0 = 0.0f, acc1 = 0.0f;
    #pragma unroll
    for (int k = 0; k < 16; ++k) {
        const int i4 = k * 1024 + tid;
        const float4 pvv = p4[i4];
        const uint2 tw = *(const uint2*)&lds_t[2 * i4];
        const float tvv[4] = {
            __uint_as_float(tw.x << 16),
            __uint_as_float(tw.x & 0xffff0000u),
            __uint_as_float(tw.y << 16),
            __uint_as_float(tw.y & 0xffff0000u)
        };
        const float pp[4] = {pvv.x, pvv.y, pvv.z, pvv.w};
        const float dr = drb + (float)(16 * k);
        const float dr2 = dr * dr;
        #pragma unroll
        for (int j = 0; j < 4; ++j) {
            const float dist = __builtin_amdgcn_sqrtf(dr2 + dc2[j]);
            const float w = 256.0f * __builtin_amdgcn_rcpf(dist + 1.0f);
            const float p = pp[j];
            const float lp  = fmaxf(__logf(p), -100.0f);          // v_log_f32
            const float l1p = fmaxf(__logf(1.0f - p), -100.0f);   // exact 1-p for p>=0.5
            // t*lp + (1-t)*l1p == l1p + t*(lp - l1p)
            if (j & 1) acc1 += w * fmaf(tvv[j], lp - l1p, l1p);
            else       acc0 += w * fmaf(tvv[j], lp - l1p, l1p);
        }
    }
    float local = acc0 + acc1;
    #pragma unroll
    for (int off = 32; off > 0; off >>= 1) local += __shfl_down(local, off);
    if (lane == 0) sm[wave] = local;   // reuse sm[]
    __syncthreads();
    if (tid == 0) {
        float s = 0.0f;
        #pragma unroll
        for (int w2 = 0; w2 < 16; ++w2) s += sm[w2];
        blocksum[frame] = (double)s;
    }
}

// Reduce 256 per-block doubles, write final loss.
__global__ __launch_bounds__(256)
void floss_final(const double* __restrict__ blocksum, float* __restrict__ out) {
    const int tid = threadIdx.x;
    const int lane = tid & 63, wave = tid >> 6;
    double v = blocksum[tid];
    #pragma unroll
    for (int off = 32; off > 0; off >>= 1) v += __shfl_down(v, off);
    __shared__ double sd[4];
    if (lane == 0) sd[wave] = v;
    __syncthreads();
    if (tid == 0)
        out[0] = (float)(-(sd[0] + sd[1] + sd[2] + sd[3]) / (double)NTOT);
}

extern "C" void kernel_launch(void* const* d_in, const int* in_sizes, int n_in,
                              void* d_out, int out_size, void* d_ws, size_t ws_size,
                              hipStream_t stream) {
    const float* input  = (const float*)d_in[0];  // [B,1,T,W,W] == flat [B,T,W,W]
    const float* target = (const float*)d_in[1];  // [B,T,W,W]
    float* out = (float*)d_out;
    double* blocksum = (double*)d_ws;             // 256 doubles, fully overwritten

    floss_fused<<<NFRAMES, BLOCK, 0, stream>>>(input, target, blocksum);
    floss_final<<<1, 256, 0, stream>>>(blocksum, out);
}